// Round 8
// baseline (6534.901 us; speedup 1.0000x reference)
//
#include <hip/hip_runtime.h>
#include <cmath>

#define NPTS 4096
#define LOG2E_F 1.4426950408889634f
#define LN2_F   0.6931471805599453f
#define BLOG_F  -8.31776616671934f   /* -ln(4096) */

#if __has_builtin(__builtin_amdgcn_exp2f)
#define EXP2F(x) __builtin_amdgcn_exp2f(x)
#else
#define EXP2F(x) exp2f(x)
#endif
#if __has_builtin(__builtin_amdgcn_logf)
#define LOG2F(x) __builtin_amdgcn_logf(x)   /* v_log_f32 = log2 */
#else
#define LOG2F(x) log2f(x)
#endif

typedef __attribute__((ext_vector_type(8))) short s16x8;
typedef __attribute__((ext_vector_type(4))) float f32x4;

#define GAS __attribute__((address_space(1)))
#define LAS __attribute__((address_space(3)))

__device__ __forceinline__ ushort bf16h(float f) {
    uint u = __float_as_uint(f);
    return (ushort)((u + 0x7fffu + ((u >> 16) & 1u)) >> 16);
}

// norms[0][b][i] = 0.5*|x|^2, norms[1][b][i] = 0.5*|y|^2; also initialize
// aux0[mat][b][i] = -rownorm(mat) so phase 0 runs as a regular phase (g=0).
__global__ __launch_bounds__(256) void norms_kernel(const float* __restrict__ x,
                                                    const float* __restrict__ y,
                                                    float* __restrict__ norms,
                                                    float* __restrict__ aux0) {
    int flat = blockIdx.x * 256 + threadIdx.x;   // 0..32767
    int which = flat >> 14;
    int rem = flat & 16383;
    int b = rem >> 12;
    int i = rem & 4095;
    const float* p = (which ? y : x) + (size_t)b * 64 * NPTS + i;
    float s = 0.f;
#pragma unroll
    for (int c = 0; c < 64; ++c) {
        float v = p[(size_t)c * NPTS];
        s += v * v;
    }
    s *= 0.5f;
    norms[flat] = s;
    aux0[(size_t)((which ? 1 : 0) * 4 + b) * NPTS + i] = -s;
    aux0[(size_t)((which ? 3 : 2) * 4 + b) * NPTS + i] = -s;
}

// bf16 prepass (hi only), fragment/staging-order layout:
//   split[(which*4+b)*32 + (n>>7)][g*128 + (n&127)][8 ushorts], g=comp octet
// Per 128-col tile: 1024 contiguous 16B chunks = 16 KB (DMA-friendly).
__global__ __launch_bounds__(256) void split_kernel(const float* __restrict__ x,
                                                    const float* __restrict__ y,
                                                    ushort* __restrict__ split) {
    int flat = blockIdx.x * 256 + threadIdx.x;   // 0..262143
    int n = flat & 4095;
    int g = (flat >> 12) & 7;
    int b = (flat >> 15) & 3;
    int which = flat >> 17;
    const float* src = (which ? y : x) + (size_t)b * 64 * NPTS + (size_t)g * 8 * NPTS + n;
    ushort hh[8];
#pragma unroll
    for (int e = 0; e < 8; ++e) hh[e] = bf16h(src[(size_t)e * NPTS]);
    uint4 hw;
    hw.x = (uint)hh[0] | ((uint)hh[1] << 16);
    hw.y = (uint)hh[2] | ((uint)hh[3] << 16);
    hw.z = (uint)hh[4] | ((uint)hh[5] << 16);
    hw.w = (uint)hh[6] | ((uint)hh[7] << 16);
    size_t dst = ((size_t)(which * 4 + b) * 32 + (n >> 7)) * 8192
               + (size_t)(g * 128 + (n & 127)) * 8;
    *(uint4*)&split[dst] = hw;
}

// Half-phase: block (b, mat, itile64, jhalf) sweeps 16 j-tiles over 64 rows.
// Plain bf16 MFMA (16/jt). Single 16 KB LDS tile; barrier-compute-barrier-DMA
// schedule so flash overlaps next DMA; 8 blocks/CU resident.
// Writes partial (m, l) per row to part[jh][mat][b][row].
__global__ __launch_bounds__(256, 8) void softmin_kernel(
    const ushort* __restrict__ split, const float* __restrict__ prevaux,
    float2* __restrict__ part, float eps)
{
    __shared__ __align__(16) ushort Bt[8192];   // 16 KB hi-only tile

    const int tid   = threadIdx.x;
    const int bid   = blockIdx.x;
    const int b     = bid & 3;
    const int mat   = (bid >> 2) & 3;
    const int jh    = (bid >> 4) & 1;
    const int itile = bid >> 5;          // 0..63

    const int row_is_x = (mat == 0 || mat == 2);
    const int col_is_x = (mat == 1 || mat == 2);
    const ushort* rowsplit = split + (size_t)((row_is_x ? 0 : 4) + b) * 32 * 8192;
    const ushort* colsplit = split + (size_t)((col_is_x ? 0 : 4) + b) * 32 * 8192;
    const int hmat = (mat == 0) ? 1 : ((mat == 1) ? 0 : mat);
    const float* hauxv = prevaux + (size_t)(hmat * 4 + b) * NPTS;
    float2* partv = part + (size_t)((jh * 4 + mat) * 4 + b) * NPTS;

    const float se      = (1.0f / eps) * LOG2E_F;
    const float epsblog = eps * BLOG_F;

    const int wave = tid >> 6;
    const int lane = tid & 63;
    const int l16  = lane & 15;    // A row / B col
    const int q    = lane >> 4;    // k-quad for A/B, row-quad for D
    const int i0   = itile * 64;
    const int arow = i0 + wave * 16 + l16;

    // ---- A fragments (bf16 hi), once per block
    s16x8 ah[2];
    {
        const ushort* abase = rowsplit + (size_t)(arow >> 7) * 8192 + (size_t)(arow & 127) * 8;
#pragma unroll
        for (int kc = 0; kc < 2; ++kc)
            ah[kc] = *(const s16x8*)&abase[(size_t)(kc * 4 + q) * 128 * 8];
    }

    const int jt0 = jh * 16;

    // ---- prologue: DMA tile jt0, prefetch its bias
    {
        const ushort* gsrc = colsplit + (size_t)jt0 * 8192;
#pragma unroll
        for (int it = 0; it < 4; ++it) {
            int chunk = it * 256 + tid;
            __builtin_amdgcn_global_load_lds(
                (const GAS uint*)(gsrc + (size_t)chunk * 8),
                (LAS uint*)(&Bt[chunk * 8]), 16, 0, 0);
        }
    }
    float hb[8];
#pragma unroll
    for (int t = 0; t < 8; ++t)
        hb[t] = epsblog + hauxv[jt0 * 128 + t * 16 + l16];

    float m[4], l[4];
#pragma unroll
    for (int r = 0; r < 4; ++r) { m[r] = -__builtin_inff(); l[r] = 0.f; }

    for (int jj = 0; jj < 16; ++jj) {
        const int jt = jt0 + jj;
        __syncthreads();   // (1) DMA for this jt complete (vmcnt drained)

        // early-issue next bias loads (drained cheaply at barrier 2)
        float hbn[8];
        if (jj < 15) {
            const float* hs = hauxv + (jt + 1) * 128;
#pragma unroll
            for (int t = 0; t < 8; ++t)
                hbn[t] = epsblog + hs[t * 16 + l16];
        }

        f32x4 acc[8];
#pragma unroll
        for (int t = 0; t < 8; ++t)
#pragma unroll
            for (int r = 0; r < 4; ++r) acc[t][r] = hb[t];

#pragma unroll
        for (int kc = 0; kc < 2; ++kc) {
            const int gofs = (kc * 4 + q) * 128 * 8;
            s16x8 bf[8];
#pragma unroll
            for (int t = 0; t < 8; ++t)
                bf[t] = *(const s16x8*)&Bt[gofs + (t * 16 + l16) * 8];
#pragma unroll
            for (int t = 0; t < 8; ++t)
                acc[t] = __builtin_amdgcn_mfma_f32_16x16x32_bf16(
                    ah[kc], bf[t], acc[t], 0, 0, 0);
        }

        __syncthreads();   // (2) all waves done reading Bt

        // DMA next tile now; flash below covers its latency in-block
        if (jj < 15) {
            const ushort* gsrc = colsplit + (size_t)(jt + 1) * 8192;
#pragma unroll
            for (int it = 0; it < 4; ++it) {
                int chunk = it * 256 + tid;
                __builtin_amdgcn_global_load_lds(
                    (const GAS uint*)(gsrc + (size_t)chunk * 8),
                    (LAS uint*)(&Bt[chunk * 8]), 16, 0, 0);
            }
        }

        // flash update: 8 cols per output-row register r
#pragma unroll
        for (int r = 0; r < 4; ++r) {
            float v0 = acc[0][r], v1 = acc[1][r], v2 = acc[2][r], v3 = acc[3][r];
            float v4 = acc[4][r], v5 = acc[5][r], v6 = acc[6][r], v7 = acc[7][r];
            float t0 = fmaxf(fmaxf(v0, v1), fmaxf(v2, v3));
            float t1 = fmaxf(fmaxf(v4, v5), fmaxf(v6, v7));
            float mn = fmaxf(fmaxf(t0, t1), m[r]);
            float tt = -se * mn;
            float e0 = EXP2F(fmaf(v0, se, tt));
            float e1 = EXP2F(fmaf(v1, se, tt));
            float e2 = EXP2F(fmaf(v2, se, tt));
            float e3 = EXP2F(fmaf(v3, se, tt));
            float e4 = EXP2F(fmaf(v4, se, tt));
            float e5 = EXP2F(fmaf(v5, se, tt));
            float e6 = EXP2F(fmaf(v6, se, tt));
            float e7 = EXP2F(fmaf(v7, se, tt));
            float rs = EXP2F(fmaf(m[r], se, tt));
            float sum = ((e0 + e1) + (e2 + e3)) + ((e4 + e5) + (e6 + e7));
            l[r] = fmaf(l[r], rs, sum);
            m[r] = mn;
        }

        if (jj < 15) {
#pragma unroll
            for (int t = 0; t < 8; ++t) hb[t] = hbn[t];
        }
    }

    // merge the 16 col-lanes (lane bits 0..3) sharing each row
#pragma unroll
    for (int off = 1; off < 16; off <<= 1) {
#pragma unroll
        for (int r = 0; r < 4; ++r) {
            float mo = __shfl_xor(m[r], off);
            float lo = __shfl_xor(l[r], off);
            float mn = fmaxf(m[r], mo);
            float tt = -se * mn;
            l[r] = fmaf(l[r], EXP2F(fmaf(m[r], se, tt)),
                        lo * EXP2F(fmaf(mo, se, tt)));
            m[r] = mn;
        }
    }

    if (l16 == 0) {
#pragma unroll
        for (int r = 0; r < 4; ++r) {
            int row = i0 + wave * 16 + q * 4 + r;   // C/D: row=(lane>>4)*4+reg
            partv[row] = make_float2(m[r], l[r]);
        }
    }
}

// Combine the two j-halves, finish the softmin, apply averaging, write f+aux.
__global__ __launch_bounds__(256) void merge_kernel(
    const float2* __restrict__ part, const float* __restrict__ norms,
    const float* __restrict__ prev, float* __restrict__ next,
    float* __restrict__ nextaux, float eps, int do_avg)
{
    int idx = blockIdx.x * 256 + threadIdx.x;   // 0..65535 = [mat][b][i]
    int i = idx & 4095;
    int b = (idx >> 12) & 3;
    int mat = idx >> 14;
    const int row_is_x = (mat == 0 || mat == 2);
    const float se     = (1.0f / eps) * LOG2E_F;
    const float epsln2 = eps * LN2_F;

    float nrm = norms[(row_is_x ? 0 : 16384) + b * NPTS + i];
    float2 p0 = part[(size_t)((0 * 4 + mat) * 4 + b) * NPTS + i];
    float2 p1 = part[(size_t)((1 * 4 + mat) * 4 + b) * NPTS + i];
    float mn = fmaxf(p0.x, p1.x);
    float lc = p0.y * EXP2F((p0.x - mn) * se) + p1.y * EXP2F((p1.x - mn) * se);
    float f = nrm - mn - epsln2 * LOG2F(lc);
    if (do_avg) f = 0.5f * (prev[idx] + f);
    next[idx] = f;
    nextaux[idx] = f - nrm;
}

// loss = [ sum_{b,i} (f_ba - f_aa) + (g_ab - g_bb) ] / (N*B)
__global__ __launch_bounds__(256) void reduce_kernel(const float* __restrict__ fin,
                                                     float* __restrict__ out) {
    float s = 0.f;
    for (int idx = threadIdx.x; idx < 4 * 4 * NPTS; idx += 256) {
        int mat = idx >> 14;
        float v = fin[idx];
        s += (mat < 2) ? v : -v;
    }
#pragma unroll
    for (int off = 32; off > 0; off >>= 1) s += __shfl_down(s, off);
    __shared__ float red[4];
    if ((threadIdx.x & 63) == 0) red[threadIdx.x >> 6] = s;
    __syncthreads();
    if (threadIdx.x == 0) {
        float t = red[0] + red[1] + red[2] + red[3];
        out[0] = t * (1.0f / (4096.0f * 4.0f));
    }
}

extern "C" void kernel_launch(void* const* d_in, const int* in_sizes, int n_in,
                              void* d_out, int out_size, void* d_ws, size_t ws_size,
                              hipStream_t stream) {
    const float* x = (const float*)d_in[0];
    const float* y = (const float*)d_in[1];
    float* out = (float*)d_out;

    float* norms = (float*)d_ws;             // 32768 floats
    float* bufA  = norms + 32768;            // 65536 floats: [mat][b][i]
    float* bufB  = bufA + 65536;
    float* auxA  = bufB + 65536;             // 65536 floats: f - rownorm
    float* auxB  = auxA + 65536;
    float2* part = (float2*)(auxB + 65536);  // 2*16*4096 float2 = 1 MB
    ushort* split = (ushort*)(part + 131072); // 4 MB bf16-hi fragments

    // eps schedule: exp(arange(2*ln16, 2*ln0.05, 2*ln0.9)) ++ [0.05^2]
    const double start = 2.0 * log(16.0);
    const double stop  = 2.0 * log(0.05);
    const double step  = 2.0 * log(0.9);
    float eps_list[64];
    int ne = 0;
    for (int k = 0;; ++k) {
        double e = start + k * step;
        if (!(e > stop)) break;
        eps_list[ne++] = (float)exp(e);
    }
    eps_list[ne++] = (float)(0.05 * 0.05);   // 56 entries

    norms_kernel<<<128, 256, 0, stream>>>(x, y, norms, auxA);
    split_kernel<<<1024, 256, 0, stream>>>(x, y, split);

    // phase 0 at eps0: aux pre-initialized to -rownorm (g=0), no averaging
    softmin_kernel<<<2048, 256, 0, stream>>>(split, auxA, part, eps_list[0]);
    merge_kernel<<<256, 256, 0, stream>>>(part, norms, bufB, bufA, auxB,
                                          eps_list[0], 0);
    float* prev = bufA;  float* prevaux = auxB;
    float* next = bufB;  float* nextaux = auxA;
    for (int t = 0; t < ne; ++t) {
        softmin_kernel<<<2048, 256, 0, stream>>>(split, prevaux, part, eps_list[t]);
        merge_kernel<<<256, 256, 0, stream>>>(part, norms, prev, next, nextaux,
                                              eps_list[t], 1);
        float* tf = prev; prev = next; next = tf;
        float* ta = prevaux; prevaux = nextaux; nextaux = ta;
    }
    // final extrapolation at eps = blur^p, no averaging
    softmin_kernel<<<2048, 256, 0, stream>>>(split, prevaux, part, eps_list[ne - 1]);
    merge_kernel<<<256, 256, 0, stream>>>(part, norms, prev, next, nextaux,
                                          eps_list[ne - 1], 0);

    reduce_kernel<<<1, 256, 0, stream>>>(next, out);
}

// Round 9
// 4070.727 us; speedup vs baseline: 1.6053x; 1.6053x over previous
//
#include <hip/hip_runtime.h>
#include <cmath>

#define NPTS 4096
#define LOG2E_F 1.4426950408889634f
#define LN2_F   0.6931471805599453f
#define BLOG_F  -8.31776616671934f   /* -ln(4096) */

#if __has_builtin(__builtin_amdgcn_exp2f)
#define EXP2F(x) __builtin_amdgcn_exp2f(x)
#else
#define EXP2F(x) exp2f(x)
#endif
#if __has_builtin(__builtin_amdgcn_logf)
#define LOG2F(x) __builtin_amdgcn_logf(x)   /* v_log_f32 = log2 */
#else
#define LOG2F(x) log2f(x)
#endif

typedef __attribute__((ext_vector_type(8))) short s16x8;
typedef __attribute__((ext_vector_type(4))) float f32x4;

#define GAS __attribute__((address_space(1)))
#define LAS __attribute__((address_space(3)))

__device__ __forceinline__ ushort bf16h(float f) {
    uint u = __float_as_uint(f);
    return (ushort)((u + 0x7fffu + ((u >> 16) & 1u)) >> 16);
}

// norms[0][b][i] = 0.5*|x|^2, norms[1][b][i] = 0.5*|y|^2; also initialize
// aux0[mat][b][i] = -rownorm(mat) so phase 0 runs as a regular phase (g=0).
__global__ __launch_bounds__(256) void norms_kernel(const float* __restrict__ x,
                                                    const float* __restrict__ y,
                                                    float* __restrict__ norms,
                                                    float* __restrict__ aux0) {
    int flat = blockIdx.x * 256 + threadIdx.x;   // 0..32767
    int which = flat >> 14;
    int rem = flat & 16383;
    int b = rem >> 12;
    int i = rem & 4095;
    const float* p = (which ? y : x) + (size_t)b * 64 * NPTS + i;
    float s = 0.f;
#pragma unroll
    for (int c = 0; c < 64; ++c) {
        float v = p[(size_t)c * NPTS];
        s += v * v;
    }
    s *= 0.5f;
    norms[flat] = s;
    aux0[(size_t)((which ? 1 : 0) * 4 + b) * NPTS + i] = -s;
    aux0[(size_t)((which ? 3 : 2) * 4 + b) * NPTS + i] = -s;
}

// bf16 prepass (hi only), fragment/staging-order layout:
//   split[(which*4+b)*32 + (n>>7)][g*128 + (n&127)][8 ushorts], g=comp octet
// Per 128-col tile: 1024 contiguous 16B chunks = 16 KB (DMA-friendly).
__global__ __launch_bounds__(256) void split_kernel(const float* __restrict__ x,
                                                    const float* __restrict__ y,
                                                    ushort* __restrict__ split) {
    int flat = blockIdx.x * 256 + threadIdx.x;   // 0..262143
    int n = flat & 4095;
    int g = (flat >> 12) & 7;
    int b = (flat >> 15) & 3;
    int which = flat >> 17;
    const float* src = (which ? y : x) + (size_t)b * 64 * NPTS + (size_t)g * 8 * NPTS + n;
    ushort hh[8];
#pragma unroll
    for (int e = 0; e < 8; ++e) hh[e] = bf16h(src[(size_t)e * NPTS]);
    uint4 hw;
    hw.x = (uint)hh[0] | ((uint)hh[1] << 16);
    hw.y = (uint)hh[2] | ((uint)hh[3] << 16);
    hw.z = (uint)hh[4] | ((uint)hh[5] << 16);
    hw.w = (uint)hh[6] | ((uint)hh[7] << 16);
    size_t dst = ((size_t)(which * 4 + b) * 32 + (n >> 7)) * 8192
               + (size_t)(g * 128 + (n & 127)) * 8;
    *(uint4*)&split[dst] = hw;
}

// Half-phase: block (b, mat, itile64, jhalf) sweeps 16 j-tiles over 64 rows.
// Plain bf16 MFMA (16/jt). Single 16 KB LDS tile; barrier-compute-barrier-DMA
// schedule so flash overlaps next DMA; 6 blocks/CU resident (85-VGPR cap,
// B-frags loaded in groups of 4 to keep peak liveness ~80).
// Writes partial (m, l) per row to part[jh][mat][b][row].
__global__ __launch_bounds__(256, 6) void softmin_kernel(
    const ushort* __restrict__ split, const float* __restrict__ prevaux,
    float2* __restrict__ part, float eps)
{
    __shared__ __align__(16) ushort Bt[8192];   // 16 KB hi-only tile

    const int tid   = threadIdx.x;
    const int bid   = blockIdx.x;
    const int b     = bid & 3;
    const int mat   = (bid >> 2) & 3;
    const int jh    = (bid >> 4) & 1;
    const int itile = bid >> 5;          // 0..63

    const int row_is_x = (mat == 0 || mat == 2);
    const int col_is_x = (mat == 1 || mat == 2);
    const ushort* rowsplit = split + (size_t)((row_is_x ? 0 : 4) + b) * 32 * 8192;
    const ushort* colsplit = split + (size_t)((col_is_x ? 0 : 4) + b) * 32 * 8192;
    const int hmat = (mat == 0) ? 1 : ((mat == 1) ? 0 : mat);
    const float* hauxv = prevaux + (size_t)(hmat * 4 + b) * NPTS;
    float2* partv = part + (size_t)((jh * 4 + mat) * 4 + b) * NPTS;

    const float se      = (1.0f / eps) * LOG2E_F;
    const float epsblog = eps * BLOG_F;

    const int wave = tid >> 6;
    const int lane = tid & 63;
    const int l16  = lane & 15;    // A row / B col
    const int q    = lane >> 4;    // k-quad for A/B, row-quad for D
    const int i0   = itile * 64;
    const int arow = i0 + wave * 16 + l16;

    // ---- A fragments (bf16 hi), once per block
    s16x8 ah[2];
    {
        const ushort* abase = rowsplit + (size_t)(arow >> 7) * 8192 + (size_t)(arow & 127) * 8;
#pragma unroll
        for (int kc = 0; kc < 2; ++kc)
            ah[kc] = *(const s16x8*)&abase[(size_t)(kc * 4 + q) * 128 * 8];
    }

    const int jt0 = jh * 16;

    // ---- prologue: DMA tile jt0, prefetch its bias
    {
        const ushort* gsrc = colsplit + (size_t)jt0 * 8192;
#pragma unroll
        for (int it = 0; it < 4; ++it) {
            int chunk = it * 256 + tid;
            __builtin_amdgcn_global_load_lds(
                (const GAS uint*)(gsrc + (size_t)chunk * 8),
                (LAS uint*)(&Bt[chunk * 8]), 16, 0, 0);
        }
    }
    float hb[8];
#pragma unroll
    for (int t = 0; t < 8; ++t)
        hb[t] = epsblog + hauxv[jt0 * 128 + t * 16 + l16];

    float m[4], l[4];
#pragma unroll
    for (int r = 0; r < 4; ++r) { m[r] = -__builtin_inff(); l[r] = 0.f; }

    for (int jj = 0; jj < 16; ++jj) {
        const int jt = jt0 + jj;
        const int jn = (jt + 1) & 31;
        __syncthreads();   // (1) DMA for this jt complete (vmcnt drained)

        // early-issue next-tile bias loads (long latency, 8 regs)
        float hbn[8];
        {
            const float* hs = hauxv + jn * 128;
#pragma unroll
            for (int t = 0; t < 8; ++t)
                hbn[t] = epsblog + hs[t * 16 + l16];
        }

        f32x4 acc[8];
#pragma unroll
        for (int t = 0; t < 8; ++t)
#pragma unroll
            for (int r = 0; r < 4; ++r) acc[t][r] = hb[t];

        // B-frags in groups of 4 (16 live regs) to stay under the VGPR cap
#pragma unroll
        for (int kc = 0; kc < 2; ++kc) {
            const int gofs = (kc * 4 + q) * 128 * 8;
#pragma unroll
            for (int tg = 0; tg < 2; ++tg) {
                s16x8 bf[4];
#pragma unroll
                for (int u = 0; u < 4; ++u)
                    bf[u] = *(const s16x8*)&Bt[gofs + ((tg * 4 + u) * 16 + l16) * 8];
#pragma unroll
                for (int u = 0; u < 4; ++u)
                    acc[tg * 4 + u] = __builtin_amdgcn_mfma_f32_16x16x32_bf16(
                        ah[kc], bf[u], acc[tg * 4 + u], 0, 0, 0);
            }
        }

        __syncthreads();   // (2) all waves done reading Bt

        // DMA next tile now; flash below covers its latency in-block
        if (jj < 15) {
            const ushort* gsrc = colsplit + (size_t)jn * 8192;
#pragma unroll
            for (int it = 0; it < 4; ++it) {
                int chunk = it * 256 + tid;
                __builtin_amdgcn_global_load_lds(
                    (const GAS uint*)(gsrc + (size_t)chunk * 8),
                    (LAS uint*)(&Bt[chunk * 8]), 16, 0, 0);
            }
        }

        // flash update: 8 cols per output-row register r
#pragma unroll
        for (int r = 0; r < 4; ++r) {
            float v0 = acc[0][r], v1 = acc[1][r], v2 = acc[2][r], v3 = acc[3][r];
            float v4 = acc[4][r], v5 = acc[5][r], v6 = acc[6][r], v7 = acc[7][r];
            float t0 = fmaxf(fmaxf(v0, v1), fmaxf(v2, v3));
            float t1 = fmaxf(fmaxf(v4, v5), fmaxf(v6, v7));
            float mn = fmaxf(fmaxf(t0, t1), m[r]);
            float tt = -se * mn;
            float e0 = EXP2F(fmaf(v0, se, tt));
            float e1 = EXP2F(fmaf(v1, se, tt));
            float e2 = EXP2F(fmaf(v2, se, tt));
            float e3 = EXP2F(fmaf(v3, se, tt));
            float e4 = EXP2F(fmaf(v4, se, tt));
            float e5 = EXP2F(fmaf(v5, se, tt));
            float e6 = EXP2F(fmaf(v6, se, tt));
            float e7 = EXP2F(fmaf(v7, se, tt));
            float rs = EXP2F(fmaf(m[r], se, tt));
            float sum = ((e0 + e1) + (e2 + e3)) + ((e4 + e5) + (e6 + e7));
            l[r] = fmaf(l[r], rs, sum);
            m[r] = mn;
        }

#pragma unroll
        for (int t = 0; t < 8; ++t) hb[t] = hbn[t];
    }

    // merge the 16 col-lanes (lane bits 0..3) sharing each row
#pragma unroll
    for (int off = 1; off < 16; off <<= 1) {
#pragma unroll
        for (int r = 0; r < 4; ++r) {
            float mo = __shfl_xor(m[r], off);
            float lo = __shfl_xor(l[r], off);
            float mn = fmaxf(m[r], mo);
            float tt = -se * mn;
            l[r] = fmaf(l[r], EXP2F(fmaf(m[r], se, tt)),
                        lo * EXP2F(fmaf(mo, se, tt)));
            m[r] = mn;
        }
    }

    if (l16 == 0) {
#pragma unroll
        for (int r = 0; r < 4; ++r) {
            int row = i0 + wave * 16 + q * 4 + r;   // C/D: row=(lane>>4)*4+reg
            partv[row] = make_float2(m[r], l[r]);
        }
    }
}

// Combine the two j-halves, finish the softmin, apply averaging, write f+aux.
__global__ __launch_bounds__(256) void merge_kernel(
    const float2* __restrict__ part, const float* __restrict__ norms,
    const float* __restrict__ prev, float* __restrict__ next,
    float* __restrict__ nextaux, float eps, int do_avg)
{
    int idx = blockIdx.x * 256 + threadIdx.x;   // 0..65535 = [mat][b][i]
    int i = idx & 4095;
    int b = (idx >> 12) & 3;
    int mat = idx >> 14;
    const int row_is_x = (mat == 0 || mat == 2);
    const float se     = (1.0f / eps) * LOG2E_F;
    const float epsln2 = eps * LN2_F;

    float nrm = norms[(row_is_x ? 0 : 16384) + b * NPTS + i];
    float2 p0 = part[(size_t)((0 * 4 + mat) * 4 + b) * NPTS + i];
    float2 p1 = part[(size_t)((1 * 4 + mat) * 4 + b) * NPTS + i];
    float mn = fmaxf(p0.x, p1.x);
    float lc = p0.y * EXP2F((p0.x - mn) * se) + p1.y * EXP2F((p1.x - mn) * se);
    float f = nrm - mn - epsln2 * LOG2F(lc);
    if (do_avg) f = 0.5f * (prev[idx] + f);
    next[idx] = f;
    nextaux[idx] = f - nrm;
}

// loss = [ sum_{b,i} (f_ba - f_aa) + (g_ab - g_bb) ] / (N*B)
__global__ __launch_bounds__(256) void reduce_kernel(const float* __restrict__ fin,
                                                     float* __restrict__ out) {
    float s = 0.f;
    for (int idx = threadIdx.x; idx < 4 * 4 * NPTS; idx += 256) {
        int mat = idx >> 14;
        float v = fin[idx];
        s += (mat < 2) ? v : -v;
    }
#pragma unroll
    for (int off = 32; off > 0; off >>= 1) s += __shfl_down(s, off);
    __shared__ float red[4];
    if ((threadIdx.x & 63) == 0) red[threadIdx.x >> 6] = s;
    __syncthreads();
    if (threadIdx.x == 0) {
        float t = red[0] + red[1] + red[2] + red[3];
        out[0] = t * (1.0f / (4096.0f * 4.0f));
    }
}

extern "C" void kernel_launch(void* const* d_in, const int* in_sizes, int n_in,
                              void* d_out, int out_size, void* d_ws, size_t ws_size,
                              hipStream_t stream) {
    const float* x = (const float*)d_in[0];
    const float* y = (const float*)d_in[1];
    float* out = (float*)d_out;

    float* norms = (float*)d_ws;             // 32768 floats
    float* bufA  = norms + 32768;            // 65536 floats: [mat][b][i]
    float* bufB  = bufA + 65536;
    float* auxA  = bufB + 65536;             // 65536 floats: f - rownorm
    float* auxB  = auxA + 65536;
    float2* part = (float2*)(auxB + 65536);  // 2*16*4096 float2 = 1 MB
    ushort* split = (ushort*)(part + 131072); // 4 MB bf16-hi fragments

    // eps schedule: exp(arange(2*ln16, 2*ln0.05, 2*ln0.9)) ++ [0.05^2]
    const double start = 2.0 * log(16.0);
    const double stop  = 2.0 * log(0.05);
    const double step  = 2.0 * log(0.9);
    float eps_list[64];
    int ne = 0;
    for (int k = 0;; ++k) {
        double e = start + k * step;
        if (!(e > stop)) break;
        eps_list[ne++] = (float)exp(e);
    }
    eps_list[ne++] = (float)(0.05 * 0.05);   // 56 entries

    norms_kernel<<<128, 256, 0, stream>>>(x, y, norms, auxA);
    split_kernel<<<1024, 256, 0, stream>>>(x, y, split);

    // phase 0 at eps0: aux pre-initialized to -rownorm (g=0), no averaging
    softmin_kernel<<<2048, 256, 0, stream>>>(split, auxA, part, eps_list[0]);
    merge_kernel<<<256, 256, 0, stream>>>(part, norms, bufB, bufA, auxB,
                                          eps_list[0], 0);
    float* prev = bufA;  float* prevaux = auxB;
    float* next = bufB;  float* nextaux = auxA;
    for (int t = 0; t < ne; ++t) {
        softmin_kernel<<<2048, 256, 0, stream>>>(split, prevaux, part, eps_list[t]);
        merge_kernel<<<256, 256, 0, stream>>>(part, norms, prev, next, nextaux,
                                              eps_list[t], 1);
        float* tf = prev; prev = next; next = tf;
        float* ta = prevaux; prevaux = nextaux; nextaux = ta;
    }
    // final extrapolation at eps = blur^p, no averaging
    softmin_kernel<<<2048, 256, 0, stream>>>(split, prevaux, part, eps_list[ne - 1]);
    merge_kernel<<<256, 256, 0, stream>>>(part, norms, prev, next, nextaux,
                                          eps_list[ne - 1], 0);

    reduce_kernel<<<1, 256, 0, stream>>>(next, out);
}